// Round 2
// baseline (1598.096 us; speedup 1.0000x reference)
//
#include <hip/hip_runtime.h>

#define BATCH 2048
#define SEQ 128
#define F 512       // INPUT_DIM == DIM == 512
#define NACT 128
#define GN_EPS 1e-5f

// ---------------------------------------------------------------------------
// Fused kernel: per (batch,tensor) block -> masked mean over SEQ + GN(1,1)
// (normalized vector kept in LDS) + embed matvec (weight rows from L1/L2).
// One extra trailing block does the action counting-sort concurrently.
// grid = 2*BATCH + 1 blocks, 512 threads.
// ---------------------------------------------------------------------------
__global__ __launch_bounds__(512) void k_fused(const float* __restrict__ pre,
                                               const float* __restrict__ eff,
                                               const int* __restrict__ action,
                                               const float* __restrict__ pw,
                                               const float* __restrict__ pb,
                                               const float* __restrict__ ew,
                                               const float* __restrict__ eb,
                                               const float* __restrict__ gamma,
                                               const float* __restrict__ beta,
                                               float* __restrict__ Ep,
                                               float* __restrict__ outE,
                                               int* __restrict__ sorted,
                                               int* __restrict__ gstart) {
    const int blk = blockIdx.x;
    const int tid = threadIdx.x;

    // ---------------- sort block (runs under the HBM phase of the others) ---
    if (blk == 2 * BATCH) {
        __shared__ int cnt[NACT];
        __shared__ int start[NACT + 1];
        if (tid < NACT) cnt[tid] = 0;
        __syncthreads();
        for (int b = tid; b < BATCH; b += 512) atomicAdd(&cnt[action[b]], 1);
        __syncthreads();
        if (tid == 0) {
            int acc = 0;
            for (int a = 0; a < NACT; ++a) { start[a] = acc; acc += cnt[a]; }
            start[NACT] = acc;
        }
        __syncthreads();
        if (tid <= NACT) gstart[tid] = start[tid];
        if (tid < NACT) cnt[tid] = start[tid];
        __syncthreads();
        for (int b = tid; b < BATCH; b += 512) {
            const int pos = atomicAdd(&cnt[action[b]], 1);
            sorted[pos] = b;
        }
        return;
    }

    // ---------------- avg + GN + embed --------------------------------------
    const int b = blk >> 1;
    const int t = blk & 1;
    const float* x = (t == 0 ? pre : eff) + (size_t)b * SEQ * F;
    const float* wmat = t == 0 ? pw : ew;
    const float* bias = t == 0 ? pb : eb;
    float* dst = (t == 0 ? Ep : outE) + (size_t)b * F;

    __shared__ float psum[4][F];
    __shared__ float pcnt[4][F];
    __shared__ float nvec[F];
    __shared__ float red[8];
    __shared__ float mv[2];

    const int g = tid >> 7;           // 0..3 : seq-phase group
    const int fb = (tid & 127) << 2;  // 0..508 : feature base (float4)

    float4 s4 = make_float4(0.f, 0.f, 0.f, 0.f);
    float4 c4 = make_float4(0.f, 0.f, 0.f, 0.f);
    for (int s = g; s < SEQ; s += 4) {
        const float4 v = *reinterpret_cast<const float4*>(x + (size_t)s * F + fb);
        s4.x += v.x; s4.y += v.y; s4.z += v.z; s4.w += v.w;
        c4.x += (v.x != 0.f) ? 1.f : 0.f;
        c4.y += (v.y != 0.f) ? 1.f : 0.f;
        c4.z += (v.z != 0.f) ? 1.f : 0.f;
        c4.w += (v.w != 0.f) ? 1.f : 0.f;
    }
    *reinterpret_cast<float4*>(&psum[g][fb]) = s4;
    *reinterpret_cast<float4*>(&pcnt[g][fb]) = c4;
    __syncthreads();

    const int f = tid;  // one feature per thread
    const float sum = psum[0][f] + psum[1][f] + psum[2][f] + psum[3][f];
    const float cntf = pcnt[0][f] + pcnt[1][f] + pcnt[2][f] + pcnt[3][f];
    const float avg = sum / cntf;  // masked mean

    const int lane = tid & 63, wv = tid >> 6;

    // mean over features
    float r = avg;
    #pragma unroll
    for (int off = 32; off; off >>= 1) r += __shfl_down(r, off, 64);
    if (lane == 0) red[wv] = r;
    __syncthreads();
    if (tid == 0) {
        float m = 0.f;
        #pragma unroll
        for (int i = 0; i < 8; ++i) m += red[i];
        mv[0] = m * (1.f / F);
    }
    __syncthreads();
    const float m = mv[0];
    const float d = avg - m;

    // variance
    r = d * d;
    #pragma unroll
    for (int off = 32; off; off >>= 1) r += __shfl_down(r, off, 64);
    if (lane == 0) red[wv] = r;
    __syncthreads();
    if (tid == 0) {
        float v = 0.f;
        #pragma unroll
        for (int i = 0; i < 8; ++i) v += red[i];
        mv[1] = v * (1.f / F);
    }
    __syncthreads();
    const float inv = 1.f / sqrtf(mv[1] + GN_EPS);

    nvec[f] = gamma[0] * d * inv + beta[0];
    __syncthreads();

    // embed: thread i computes dot(weight row i, nvec) + bias[i].
    // weight rows are hot in L1/L2 (1 MB matrix, every block re-reads it);
    // nvec reads are same-address LDS broadcasts (conflict-free).
    const float* wr = wmat + (size_t)f * F;
    float acc0 = 0.f, acc1 = 0.f;
    #pragma unroll 4
    for (int k = 0; k < F; k += 8) {
        const float4 w0 = *reinterpret_cast<const float4*>(wr + k);
        const float4 w1 = *reinterpret_cast<const float4*>(wr + k + 4);
        const float4 n0 = *reinterpret_cast<const float4*>(&nvec[k]);
        const float4 n1 = *reinterpret_cast<const float4*>(&nvec[k + 4]);
        acc0 = fmaf(w0.x, n0.x, acc0); acc0 = fmaf(w0.y, n0.y, acc0);
        acc0 = fmaf(w0.z, n0.z, acc0); acc0 = fmaf(w0.w, n0.w, acc0);
        acc1 = fmaf(w1.x, n1.x, acc1); acc1 = fmaf(w1.y, n1.y, acc1);
        acc1 = fmaf(w1.z, n1.z, acc1); acc1 = fmaf(w1.w, n1.w, acc1);
    }
    dst[f] = acc0 + acc1 + bias[f];
}

// ---------------------------------------------------------------------------
// Transform: p_transformed[b,:] = W[action[b]] @ Ep[b,:], action-grouped.
// grid (NACT, 8): 64 rows per block, 4 waves x 16 rows; lanes split the
// 512-wide dot (8 floats/lane), 8 batches register-blocked, shuffle-reduce.
// ---------------------------------------------------------------------------
__global__ __launch_bounds__(256) void k_transform(const float* __restrict__ W,
                                                   const float* __restrict__ Ep,
                                                   const int* __restrict__ sorted,
                                                   const int* __restrict__ gstart,
                                                   float* __restrict__ outP) {
    const int a = blockIdx.x;
    const int s0 = gstart[a], s1 = gstart[a + 1];
    if (s0 == s1) return;

    const int rowbase = blockIdx.y * 64 + (threadIdx.x >> 6) * 16;
    const int lane = threadIdx.x & 63;
    const float* Wa = W + (size_t)a * F * F;

    for (int c0 = s0; c0 < s1; c0 += 8) {
        int bb[8];
        float4 e0[8], e1[8];
        #pragma unroll
        for (int q = 0; q < 8; ++q) {
            const int src = (c0 + q < s1) ? (c0 + q) : s0;  // pad with valid idx
            bb[q] = sorted[src];
            const float* er = Ep + (size_t)bb[q] * F + lane * 8;
            e0[q] = *reinterpret_cast<const float4*>(er);
            e1[q] = *reinterpret_cast<const float4*>(er + 4);
        }
        for (int r = 0; r < 16; ++r) {
            const int i = rowbase + r;
            const float* wr = Wa + (size_t)i * F + lane * 8;
            const float4 w0 = *reinterpret_cast<const float4*>(wr);
            const float4 w1 = *reinterpret_cast<const float4*>(wr + 4);
            float p[8];
            #pragma unroll
            for (int q = 0; q < 8; ++q) {
                float s = w0.x * e0[q].x;
                s = fmaf(w0.y, e0[q].y, s);
                s = fmaf(w0.z, e0[q].z, s);
                s = fmaf(w0.w, e0[q].w, s);
                s = fmaf(w1.x, e1[q].x, s);
                s = fmaf(w1.y, e1[q].y, s);
                s = fmaf(w1.z, e1[q].z, s);
                s = fmaf(w1.w, e1[q].w, s);
                p[q] = s;
            }
            #pragma unroll
            for (int q = 0; q < 8; ++q) {
                #pragma unroll
                for (int off = 32; off; off >>= 1) p[q] += __shfl_down(p[q], off, 64);
            }
            if (lane == 0) {
                #pragma unroll
                for (int q = 0; q < 8; ++q)
                    if (c0 + q < s1) outP[(size_t)bb[q] * F + i] = p[q];
            }
        }
    }
}

// ---------------------------------------------------------------------------
extern "C" void kernel_launch(void* const* d_in, const int* in_sizes, int n_in,
                              void* d_out, int out_size, void* d_ws, size_t ws_size,
                              hipStream_t stream) {
    const float* pre    = (const float*)d_in[0];
    const float* eff    = (const float*)d_in[1];
    const int*   action = (const int*)d_in[2];
    const float* W      = (const float*)d_in[3];
    const float* pw     = (const float*)d_in[4];
    const float* pb     = (const float*)d_in[5];
    const float* ew     = (const float*)d_in[6];
    const float* eb     = (const float*)d_in[7];
    const float* gamma  = (const float*)d_in[8];
    const float* beta   = (const float*)d_in[9];

    float* out  = (float*)d_out;
    float* outP = out;                     // [2048,512] p_transformed
    float* outE = out + (size_t)BATCH * F; // [2048,512] e_embed

    // workspace: Ep | sorted | gstart  (~4.2 MB)
    float* Ep = (float*)d_ws;
    int* sorted = (int*)(Ep + (size_t)BATCH * F);
    int* gstart = sorted + BATCH;

    k_fused<<<2 * BATCH + 1, 512, 0, stream>>>(pre, eff, action, pw, pb, ew, eb,
                                               gamma, beta, Ep, outE, sorted, gstart);
    k_transform<<<dim3(NACT, 8), 256, 0, stream>>>(W, Ep, sorted, gstart, outP);
}